// Round 6
// baseline (1006.120 us; speedup 1.0000x reference)
//
#include <hip/hip_runtime.h>
#include <stdint.h>

// H2GCN forward on MI355X (gfx950). Round 12:
//  - r11 post-mortem: SPMM ~370us total, L3-bound (12.8MB gather table >
//    4MB/XCD L2; per-XCD L2s private -> gathers miss to L3).
//  - SPMM v12: channel-quartered gather tables, QUARTER-MAJOR layout
//    ([q][node][16ch], 3.2MB/quarter fits one XCD L2). Block's quarter
//    q=(blockIdx&7)&3 rides the round-robin blockIdx->XCD mapping so each
//    XCD gathers from a resident 3.2MB slice. 8 edges/instr x 8 lanes x 4B;
//    32 edges in flight; shfl_xor(8/16/32) reduce.
//  - k_embed writes hb quarter-major; sp passes write successor tables
//    quarter-major (hi bf16) alongside row-major z planes for k_final.
//  - k_embed GEMM core / k_final / graph build unchanged.

typedef __bf16 bf16x8 __attribute__((ext_vector_type(8)));
typedef float  f32x4  __attribute__((ext_vector_type(4)));

#define NN   100000
#define EE   800000
#define IND  512
#define HID  64
#define ZD   320
#define CLS  40
#define NCH  98           // ceil(NN/1024)
#define NBLKE 1563        // ceil(NN/64) embed blocks (4 waves x 16 rows)
#define QSZ  (NN * 16)    // shorts per quarter-plane

static __device__ __forceinline__ float bf2f(unsigned short s) {
  unsigned int u = ((unsigned int)s) << 16;
  return __builtin_bit_cast(float, u);
}
static __device__ __forceinline__ unsigned short f2bf(float f) {
  unsigned int u = __builtin_bit_cast(unsigned int, f);
  u += 0x7FFFu + ((u >> 16) & 1u);   // RNE
  return (unsigned short)(u >> 16);
}
static __device__ __forceinline__ float ldsc(const void* p, int i, int fm) {
  return fm ? ((const float*)p)[i] : bf2f(((const unsigned short*)p)[i]);
}
static __device__ __forceinline__ float i2f(int v) { return __builtin_bit_cast(float, v); }
static __device__ __forceinline__ void split8r(f32x4 u0, f32x4 u1, bf16x8& hi, bf16x8& lo) {
  #pragma unroll
  for (int j = 0; j < 4; ++j) {
    float v0 = u0[j], v1 = u1[j];
    __bf16 h0 = (__bf16)v0, h1 = (__bf16)v1;
    hi[j] = h0;     lo[j] = (__bf16)(v0 - (float)h0);
    hi[4 + j] = h1; lo[4 + j] = (__bf16)(v1 - (float)h1);
  }
}
static __device__ __forceinline__ void splitsc(float v, unsigned short* hp, unsigned short* lp) {
  __bf16 h = (__bf16)v;
  *hp = __builtin_bit_cast(unsigned short, h);
  __bf16 l = (__bf16)(v - (float)h);
  *lp = __builtin_bit_cast(unsigned short, l);
}
// split 2 channels, pack, 4B stores to hi/lo planes
static __device__ __forceinline__ void split2(float x, float y,
                                              unsigned short* hp, unsigned short* lp) {
  __bf16 hx = (__bf16)x, hy = (__bf16)y;
  __bf16 lx = (__bf16)(x - (float)hx), ly = (__bf16)(y - (float)hy);
  unsigned int hw = (unsigned int)__builtin_bit_cast(unsigned short, hx)
                  | ((unsigned int)__builtin_bit_cast(unsigned short, hy) << 16);
  unsigned int lw = (unsigned int)__builtin_bit_cast(unsigned short, lx)
                  | ((unsigned int)__builtin_bit_cast(unsigned short, ly) << 16);
  *(unsigned int*)hp = hw;
  *(unsigned int*)lp = lw;
}
// async global->LDS, 16B per lane (dest = uniform base + lane*16)
static __device__ __forceinline__ void gload16(const void* g, void* l) {
  __builtin_amdgcn_global_load_lds(
      (const __attribute__((address_space(1))) void*)g,
      (__attribute__((address_space(3))) void*)l, 16, 0, 0);
}

// ---------------- dtype probe ----------------
__global__ void k_probe(const unsigned short* __restrict__ xs,
                        const int* __restrict__ ei, int* __restrict__ flags) {
  __shared__ int cnt_big, cnt_nz;
  if (threadIdx.x == 0) { cnt_big = 0; cnt_nz = 0; }
  __syncthreads();
  unsigned short u = xs[threadIdx.x];
  int expf = (u >> 7) & 0xFF;
  if (expf >= 0x8D) atomicAdd(&cnt_big, 1);
  if (threadIdx.x < 128 && ei[2 * threadIdx.x + 1] != 0) atomicAdd(&cnt_nz, 1);
  __syncthreads();
  if (threadIdx.x == 0) {
    flags[0] = (cnt_big >= 2) ? 1 : 0;
    flags[1] = (cnt_nz < 64) ? 1 : 0;
  }
}

// ---------------- weight pre-split (W1, W2) ----------------
__global__ void k_wsplit(const void* __restrict__ Wv, const int* __restrict__ flags,
                         int n, unsigned short* __restrict__ hi,
                         unsigned short* __restrict__ lo) {
  int i = blockIdx.x * 256 + threadIdx.x;
  if (i >= n) return;
  float v = ldsc(Wv, i, flags[0]);
  splitsc(v, hi + i, lo + i);
}

// ---------------- embed-W split + pack into MFMA fragment order -------------
__global__ void k_wpack(const void* __restrict__ Wv, const int* __restrict__ flags,
                        unsigned short* __restrict__ ph, unsigned short* __restrict__ pl) {
  int tid = blockIdx.x * 256 + threadIdx.x;
  if (tid >= 64 * 64) return;
  int f = tid >> 6, lane = tid & 63;
  int kk = f >> 2, nt = f & 3;
  int l15 = lane & 15, quad = lane >> 4;
  int fmv = flags[0];
  int src = (nt * 16 + l15) * IND + kk * 32 + quad * 8;
  size_t dst = ((size_t)f * 64 + lane) * 8;
  #pragma unroll
  for (int j = 0; j < 8; ++j) {
    float v = ldsc(Wv, src + j, fmv);
    splitsc(v, ph + dst + j, pl + dst + j);
  }
}

// ---------------- graph build ----------------
__global__ void k_deg(const int* __restrict__ ei, const int* __restrict__ flags,
                      int* __restrict__ deg) {
  int e = blockIdx.x * 256 + threadIdx.x;
  if (e >= EE) return;
  int r, c;
  if (flags[1]) { r = ((const int2*)ei)[e].x; c = ((const int2*)ei)[EE + e].x; }
  else          { r = ei[e];                  c = ei[EE + e]; }
  if (r != c) { atomicAdd(&deg[r], 1); atomicAdd(&deg[c], 1); }
}

__global__ void k_chunksum(const int* __restrict__ deg, int* __restrict__ csum) {
  __shared__ int sd[1024];
  int i = blockIdx.x * 1024 + threadIdx.x;
  sd[threadIdx.x] = (i < NN) ? deg[i] : 0;
  __syncthreads();
  for (int s = 512; s > 0; s >>= 1) {
    if (threadIdx.x < s) sd[threadIdx.x] += sd[threadIdx.x + s];
    __syncthreads();
  }
  if (threadIdx.x == 0) csum[blockIdx.x] = sd[0];
}

__global__ void k_scanchunks(int* __restrict__ csum, int* __restrict__ total) {
  if (threadIdx.x == 0) {
    int acc = 0;
    for (int i = 0; i < NCH; ++i) { int v = csum[i]; csum[i] = acc; acc += v; }
    total[0] = acc;
  }
}

__global__ void k_offs(const int* __restrict__ deg, const int* __restrict__ cbase,
                       int* __restrict__ offs, float* __restrict__ dinv) {
  __shared__ int sd[1024];
  int i = blockIdx.x * 1024 + threadIdx.x;
  int v = (i < NN) ? deg[i] : 0;
  sd[threadIdx.x] = v;
  __syncthreads();
  for (int s = 1; s < 1024; s <<= 1) {
    int t = (threadIdx.x >= s) ? sd[threadIdx.x - s] : 0;
    __syncthreads();
    sd[threadIdx.x] += t;
    __syncthreads();
  }
  if (i < NN) {
    offs[i] = cbase[blockIdx.x] + sd[threadIdx.x] - v;
    dinv[i] = (v > 0) ? rsqrtf((float)v) : 0.f;
  }
}

__global__ void k_fill(const int* __restrict__ ei, const int* __restrict__ flags,
                       const int* __restrict__ offs,
                       int* __restrict__ fill, const float* __restrict__ dinv,
                       int2* __restrict__ ep) {
  int e = blockIdx.x * 256 + threadIdx.x;
  if (e >= EE) return;
  int r, c;
  if (flags[1]) { r = ((const int2*)ei)[e].x; c = ((const int2*)ei)[EE + e].x; }
  else          { r = ei[e];                  c = ei[EE + e]; }
  if (r == c) return;
  float w = dinv[r] * dinv[c];
  int wb = __builtin_bit_cast(int, w);
  int p = offs[r] + atomicAdd(&fill[r], 1);
  ep[p] = make_int2(c, wb);
  int q = offs[c] + atomicAdd(&fill[c], 1);
  ep[q] = make_int2(r, wb);
}

// ---------------- embed GEMM: g_hb = bf16(relu(x @ W^T + b)), + BN stats -----
// v10 structure; hb store is now quarter-major: g_hb[nt*QSZ + row*16 + l15].
__global__ __launch_bounds__(256, 4) void k_embed(
    const void* __restrict__ xv,
    const unsigned short* __restrict__ wph, const unsigned short* __restrict__ wpl,
    const void* __restrict__ bEv, const int* __restrict__ flags,
    unsigned short* __restrict__ g_hb, float* __restrict__ bnsum, float* __restrict__ bnsq) {
  __shared__ char xb[2][16384] __attribute__((aligned(128)));
  __shared__ float ssum[4][64];
  __shared__ float ssq[4][64];
  const int fm = flags[0];
  const int wave = threadIdx.x >> 6, lane = threadIdx.x & 63;
  const int l15 = lane & 15, quad = lane >> 4;
  const int rb = blockIdx.x * 64;
  const int rbw = rb + wave * 16;
  f32x4 acc[4] = {};
  if (fm) {
    const char* sp[4];
    {
      const int borig = (l15 ^ (quad & 1)) * 16;
      #pragma unroll
      for (int j = 0; j < 4; ++j) {
        int grow = rb + (wave * 4 + j) * 4 + quad;
        if (grow > NN - 1) grow = NN - 1;
        sp[j] = (const char*)xv + (size_t)grow * 2048 + borig;
      }
    }
    const int p = l15 & 1;
    const int roA = (wave * 16 + l15) * 256 + quad * 32 + 16 * p;
    const int roB = (wave * 16 + l15) * 256 + quad * 32 + 16 - 16 * p;
    #pragma unroll
    for (int j = 0; j < 4; ++j)
      gload16(sp[j], &xb[0][(wave * 4 + j) * 1024]);
    __syncthreads();
    for (int c = 0; c < 8; ++c) {
      const int cur = c & 1;
      bf16x8 bh[2][4], bl[2][4];
      #pragma unroll
      for (int ks = 0; ks < 2; ++ks)
        #pragma unroll
        for (int nt = 0; nt < 4; ++nt) {
          size_t off = ((size_t)((c * 2 + ks) * 4 + nt) * 64 + lane) * 8;
          bh[ks][nt] = *(const bf16x8*)(wph + off);
          bl[ks][nt] = *(const bf16x8*)(wpl + off);
        }
      __builtin_amdgcn_sched_barrier(0);
      if (c < 7) {
        char* db = &xb[cur ^ 1][0];
        #pragma unroll
        for (int j = 0; j < 4; ++j)
          gload16(sp[j] + (c + 1) * 256, db + (wave * 4 + j) * 1024);
      }
      __builtin_amdgcn_sched_barrier(0);
      const char* cb = &xb[cur][0];
      #pragma unroll
      for (int ks = 0; ks < 2; ++ks) {
        f32x4 u0 = *(const f32x4*)(cb + roA + ks * 128);
        f32x4 u1 = *(const f32x4*)(cb + roB + ks * 128);
        bf16x8 ahi, alo;
        split8r(u0, u1, ahi, alo);
        #pragma unroll
        for (int nt = 0; nt < 4; ++nt) {
          acc[nt] = __builtin_amdgcn_mfma_f32_16x16x32_bf16(ahi, bh[ks][nt], acc[nt], 0, 0, 0);
          acc[nt] = __builtin_amdgcn_mfma_f32_16x16x32_bf16(alo, bh[ks][nt], acc[nt], 0, 0, 0);
          acc[nt] = __builtin_amdgcn_mfma_f32_16x16x32_bf16(ahi, bl[ks][nt], acc[nt], 0, 0, 0);
        }
      }
      __syncthreads();
    }
  } else {
    int row0 = rbw + l15; if (row0 > NN - 1) row0 = NN - 1;
    const unsigned short* xr0 = (const unsigned short*)xv + (size_t)row0 * IND + quad * 8;
    for (int kk = 0; kk < 16; ++kk) {
      bf16x8 bh[4];
      #pragma unroll
      for (int nt = 0; nt < 4; ++nt)
        bh[nt] = *(const bf16x8*)(wph + ((size_t)(kk * 4 + nt) * 64 + lane) * 8);
      bf16x8 a0 = *(const bf16x8*)(xr0 + kk * 32);
      #pragma unroll
      for (int nt = 0; nt < 4; ++nt)
        acc[nt] = __builtin_amdgcn_mfma_f32_16x16x32_bf16(a0, bh[nt], acc[nt], 0, 0, 0);
    }
  }
  #pragma unroll
  for (int nt = 0; nt < 4; ++nt) {
    int n = nt * 16 + l15;
    float bb = ldsc(bEv, n, fm);
    float ps = 0.f, pq = 0.f;
    #pragma unroll
    for (int r = 0; r < 4; ++r) {
      int row = rbw + quad * 4 + r;
      if (row < NN) {
        float v = fmaxf(acc[nt][r] + bb, 0.f);
        g_hb[(size_t)nt * QSZ + ((size_t)row << 4) + l15] = f2bf(v);
        ps += v; pq += v * v;
      }
    }
    ps += __shfl_xor(ps, 16); pq += __shfl_xor(pq, 16);
    ps += __shfl_xor(ps, 32); pq += __shfl_xor(pq, 32);
    if (quad == 0) { ssum[wave][n] = ps; ssq[wave][n] = pq; }
  }
  __syncthreads();
  if (threadIdx.x < 64) {
    int c = threadIdx.x;
    float s = ssum[0][c] + ssum[1][c] + ssum[2][c] + ssum[3][c];
    float q = ssq[0][c] + ssq[1][c] + ssq[2][c] + ssq[3][c];
    atomicAdd(&bnsum[c], s);
    atomicAdd(&bnsq[c], q);
  }
}

__global__ void k_bnfin(const float* __restrict__ bnsum, const float* __restrict__ bnsq,
                        const void* __restrict__ gv, const void* __restrict__ bv,
                        const int* __restrict__ flags, float* __restrict__ ab) {
  int c = threadIdx.x;
  int fm = flags[0];
  if (c < 64) {
    float mu = bnsum[c] * (1.0f / (float)NN);
    float var = bnsq[c] * (1.0f / (float)NN) - mu * mu;
    float a = ldsc(gv, c, fm) / sqrtf(var + 1e-5f);
    float b = ldsc(bv, c, fm) - mu * a;
    ab[c] = a; ab[64 + c] = b;
  }
}

// ---------------- SPMM: channel-quartered XCD-local gather ----------------
// Block b: x=b&7 (XCD), quarter q=x&3, rowgroup rg=(b>>3)*2+(x>>2); wave owns
// row r=rg*4+wave. Lane: g3=lane>>3 edge slot (8 edges/instr), c3=lane&7 owns
// channels q*16+2c3,+1 (dword). 32 edges in flight; masked tails (w=0).
// GSRC = quarter-plane base (bf16, [node][16ch] contiguous, 32B rows).
#define PGQ(GSRC)                                                              \
  float2 a2[4] = {}; float sw = 0.f, sq = 0.f; (void)sq;                       \
  for (int i = s; i < e; i += 32) {                                            \
    int2 qe[4]; float wv[4];                                                   \
    _Pragma("unroll") for (int t = 0; t < 4; ++t) {                            \
      int jj = i + t * 8 + g3;                                                 \
      bool ok = jj < e;                                                        \
      qe[t] = ep[ok ? jj : s];                                                 \
      wv[t] = ok ? i2f(qe[t].y) : 0.f;                                         \
    }                                                                          \
    unsigned int vv[4];                                                        \
    _Pragma("unroll") for (int t = 0; t < 4; ++t)                              \
      vv[t] = *(const unsigned int*)(GSRC + (((size_t)qe[t].x) << 4) + 2 * c3);\
    _Pragma("unroll") for (int t = 0; t < 4; ++t) {                            \
      a2[t].x = fmaf(wv[t], bf2f((unsigned short)(vv[t] & 0xffff)), a2[t].x);  \
      a2[t].y = fmaf(wv[t], bf2f((unsigned short)(vv[t] >> 16)), a2[t].y);     \
      sw += wv[t]; sq = fmaf(wv[t], wv[t], sq);                                \
    }                                                                          \
  }                                                                            \
  float accx = (a2[0].x + a2[1].x) + (a2[2].x + a2[3].x);                      \
  float accy = (a2[0].y + a2[1].y) + (a2[2].y + a2[3].y);                      \
  accx += __shfl_xor(accx, 8);  accy += __shfl_xor(accy, 8);                   \
  sw   += __shfl_xor(sw, 8);    sq   += __shfl_xor(sq, 8);                     \
  accx += __shfl_xor(accx, 16); accy += __shfl_xor(accy, 16);                  \
  sw   += __shfl_xor(sw, 16);   sq   += __shfl_xor(sq, 16);                    \
  accx += __shfl_xor(accx, 32); accy += __shfl_xor(accy, 32);                  \
  sw   += __shfl_xor(sw, 32);   sq   += __shfl_xor(sq, 32);

#define SPDECOMP                                                               \
  const int xq = blockIdx.x & 7;                                               \
  const int q = xq & 3;                                                        \
  const int rg = ((blockIdx.x >> 3) << 1) + (xq >> 2);                         \
  const int wave = threadIdx.x >> 6, lane = threadIdx.x & 63;                  \
  const int r = rg * 4 + wave;                                                 \
  const int g3 = lane >> 3, c3 = lane & 7;                                     \
  const int ch = q * 16 + 2 * c3;

// SPMM1: gather g_hb; z block0 = BN(hb[r]); block1 = h1 (+ g_h1); diag2
__global__ __launch_bounds__(256) void k_sp1(
    const int* __restrict__ offs, const int2* __restrict__ ep,
    const unsigned short* __restrict__ g_hb, const float* __restrict__ bnab,
    float* __restrict__ diag2,
    unsigned short* __restrict__ zhi, unsigned short* __restrict__ zlo,
    unsigned short* __restrict__ g_h1) {
  SPDECOMP
  int s = offs[r], e = offs[r + 1];
  const unsigned short* gq = g_hb + (size_t)q * QSZ;
  PGQ(gq)
  float2 ga = *(const float2*)(bnab + ch);
  float2 gb = *(const float2*)(bnab + 64 + ch);
  unsigned int hv = *(const unsigned int*)(gq + (((size_t)r) << 4) + 2 * c3);
  float z0x = fmaf(ga.x, bf2f((unsigned short)(hv & 0xffff)), gb.x);
  float z0y = fmaf(ga.y, bf2f((unsigned short)(hv >> 16)), gb.y);
  float h1x = ga.x * accx + gb.x * sw;
  float h1y = ga.y * accy + gb.y * sw;
  if (g3 == 0) {
    size_t zr = (size_t)r * ZD + ch;
    split2(z0x, z0y, zhi + zr, zlo + zr);
    split2(h1x, h1y, zhi + zr + 64, zlo + zr + 64);
    unsigned int hw = (unsigned int)f2bf(h1x) | ((unsigned int)f2bf(h1y) << 16);
    *(unsigned int*)(g_h1 + (size_t)q * QSZ + (((size_t)r) << 4) + 2 * c3) = hw;
  }
  if (q == 0 && lane == 0) diag2[r] = sq;
}

// SPMM2: gather g_h1; h2 = acc - diag2*z0; z block2 = h2; g_cur = bf16(h1+h2)
__global__ __launch_bounds__(256) void k_sp2(
    const int* __restrict__ offs, const int2* __restrict__ ep,
    const unsigned short* __restrict__ g_h1, const float* __restrict__ diag2,
    unsigned short* __restrict__ zhi, unsigned short* __restrict__ zlo,
    unsigned short* __restrict__ g_cur) {
  SPDECOMP
  int s = offs[r], e = offs[r + 1];
  const unsigned short* gq = g_h1 + (size_t)q * QSZ;
  PGQ(gq)
  size_t zr = (size_t)r * ZD + ch;
  unsigned int zh0 = *(const unsigned int*)(zhi + zr);
  unsigned int zl0 = *(const unsigned int*)(zlo + zr);
  unsigned int zh1 = *(const unsigned int*)(zhi + zr + 64);
  unsigned int zl1 = *(const unsigned int*)(zlo + zr + 64);
  float z0x = bf2f((unsigned short)(zh0 & 0xffff)) + bf2f((unsigned short)(zl0 & 0xffff));
  float z0y = bf2f((unsigned short)(zh0 >> 16)) + bf2f((unsigned short)(zl0 >> 16));
  float h1x = bf2f((unsigned short)(zh1 & 0xffff)) + bf2f((unsigned short)(zl1 & 0xffff));
  float h1y = bf2f((unsigned short)(zh1 >> 16)) + bf2f((unsigned short)(zl1 >> 16));
  float d2 = diag2[r];
  float h2x = accx - d2 * z0x;
  float h2y = accy - d2 * z0y;
  if (g3 == 0) {
    split2(h2x, h2y, zhi + zr + 128, zlo + zr + 128);
    unsigned int cw = (unsigned int)f2bf(h1x + h2x) | ((unsigned int)f2bf(h1y + h2y) << 16);
    *(unsigned int*)(g_cur + (size_t)q * QSZ + (((size_t)r) << 4) + 2 * c3) = cw;
  }
}

// SPMM3/4: gather g_src; y = acc [- diag2*bf(g_corr)]; z block zoff = y
// (+ optional g_dst quarter-major copy for the next pass's gather source)
__global__ __launch_bounds__(256) void k_spg(
    const int* __restrict__ offs, const int2* __restrict__ ep,
    const unsigned short* __restrict__ g_src, const float* __restrict__ diag2,
    const unsigned short* __restrict__ g_corr,
    unsigned short* __restrict__ zhi, unsigned short* __restrict__ zlo, long zoff,
    unsigned short* __restrict__ g_dst) {
  SPDECOMP
  int s = offs[r], e = offs[r + 1];
  const unsigned short* gq = g_src + (size_t)q * QSZ;
  PGQ(gq)
  if (g_corr) {
    float d2 = diag2[r];
    unsigned int cv = *(const unsigned int*)(g_corr + (size_t)q * QSZ + (((size_t)r) << 4) + 2 * c3);
    accx -= d2 * bf2f((unsigned short)(cv & 0xffff));
    accy -= d2 * bf2f((unsigned short)(cv >> 16));
  }
  if (g3 == 0) {
    size_t zi = (size_t)r * ZD + zoff + ch;
    split2(accx, accy, zhi + zi, zlo + zi);
    if (g_dst) {
      unsigned int dw = (unsigned int)f2bf(accx) | ((unsigned int)f2bf(accy) << 16);
      *(unsigned int*)(g_dst + (size_t)q * QSZ + (((size_t)r) << 4) + 2 * c3) = dw;
    }
  }
}

// ---------------- final: out = relu(z @ W1^T + b1) @ W2^T + b2 ----------------
__global__ __launch_bounds__(256) void k_final(
    const unsigned short* __restrict__ zhi, const unsigned short* __restrict__ zlo,
    const unsigned short* __restrict__ w1hi, const unsigned short* __restrict__ w1lo,
    const void* __restrict__ b1v,
    const unsigned short* __restrict__ w2hi, const unsigned short* __restrict__ w2lo,
    const void* __restrict__ b2v,
    const int* __restrict__ flags, void* __restrict__ outv) {
  __shared__ float tls[4][2][16][68];
  const int fm = flags[0];
  const int wave = threadIdx.x >> 6, lane = threadIdx.x & 63;
  const int l15 = lane & 15, quad = lane >> 4;
  const int gid = blockIdx.x * 4 + wave;      // 0..3124 valid (32 rows each)
  const bool valid = gid < NN / 32;
  if (valid) {
    const int rb = gid * 32;
    f32x4 acc[2][4] = {};
    size_t zb[2];
    #pragma unroll
    for (int t = 0; t < 2; ++t)
      zb[t] = (size_t)(rb + t * 16 + l15) * ZD + quad * 8;
    for (int ks = 0; ks < 10; ++ks) {
      bf16x8 ahi[2], alo[2];
      #pragma unroll
      for (int t = 0; t < 2; ++t) {
        ahi[t] = *(const bf16x8*)(zhi + zb[t] + ks * 32);
        alo[t] = *(const bf16x8*)(zlo + zb[t] + ks * 32);
      }
      #pragma unroll
      for (int nt = 0; nt < 4; ++nt) {
        size_t wb = (size_t)(nt * 16 + l15) * ZD + ks * 32 + quad * 8;
        bf16x8 bhi = *(const bf16x8*)(w1hi + wb);
        bf16x8 blo = *(const bf16x8*)(w1lo + wb);
        #pragma unroll
        for (int t = 0; t < 2; ++t) {
          acc[t][nt] = __builtin_amdgcn_mfma_f32_16x16x32_bf16(ahi[t], bhi, acc[t][nt], 0, 0, 0);
          acc[t][nt] = __builtin_amdgcn_mfma_f32_16x16x32_bf16(alo[t], bhi, acc[t][nt], 0, 0, 0);
          acc[t][nt] = __builtin_amdgcn_mfma_f32_16x16x32_bf16(ahi[t], blo, acc[t][nt], 0, 0, 0);
        }
      }
    }
    #pragma unroll
    for (int nt = 0; nt < 4; ++nt) {
      int n = nt * 16 + l15;
      float bb = ldsc(b1v, n, fm);
      #pragma unroll
      for (int t = 0; t < 2; ++t)
        #pragma unroll
        for (int r = 0; r < 4; ++r)
          tls[wave][t][quad * 4 + r][n] = fmaxf(acc[t][nt][r] + bb, 0.f);
    }
  }
  __syncthreads();
  if (valid) {
    const int rb = gid * 32;
    f32x4 acc2[2][3] = {};
    #pragma unroll
    for (int ks = 0; ks < 2; ++ks) {
      bf16x8 ahi[2], alo[2];
      #pragma unroll
      for (int t = 0; t < 2; ++t)
        #pragma unroll
        for (int j = 0; j < 8; ++j) {
          float v = tls[wave][t][l15][ks * 32 + quad * 8 + j];
          __bf16 h = (__bf16)v;
          ahi[t][j] = h; alo[t][j] = (__bf16)(v - (float)h);
        }
      #pragma unroll
      for (int nt = 0; nt < 3; ++nt) {
        int n = nt * 16 + l15;
        bf16x8 bhi = {}, blo = {};
        if (n < CLS) {
          size_t wb = (size_t)n * HID + ks * 32 + quad * 8;
          bhi = *(const bf16x8*)(w2hi + wb);
          blo = *(const bf16x8*)(w2lo + wb);
        }
        #pragma unroll
        for (int t = 0; t < 2; ++t) {
          acc2[t][nt] = __builtin_amdgcn_mfma_f32_16x16x32_bf16(ahi[t], bhi, acc2[t][nt], 0, 0, 0);
          acc2[t][nt] = __builtin_amdgcn_mfma_f32_16x16x32_bf16(alo[t], bhi, acc2[t][nt], 0, 0, 0);
          acc2[t][nt] = __builtin_amdgcn_mfma_f32_16x16x32_bf16(ahi[t], blo, acc2[t][nt], 0, 0, 0);
        }
      }
    }
    #pragma unroll
    for (int nt = 0; nt < 3; ++nt) {
      int n = nt * 16 + l15;
      if (n < CLS) {
        float bb = ldsc(b2v, n, fm);
        #pragma unroll
        for (int t = 0; t < 2; ++t)
          #pragma unroll
          for (int r = 0; r < 4; ++r) {
            float v = acc2[t][nt][r] + bb;
            size_t oi = (size_t)(rb + t * 16 + quad * 4 + r) * CLS + n;
            if (fm) ((float*)outv)[oi] = v;
            else    ((unsigned short*)outv)[oi] = f2bf(v);
          }
      }
    }
  }
}

extern "C" void kernel_launch(void* const* d_in, const int* in_sizes, int n_in,
                              void* d_out, int out_size, void* d_ws, size_t ws_size,
                              hipStream_t stream) {
  (void)in_sizes; (void)n_in; (void)out_size; (void)ws_size;
  const void* x   = d_in[0];
  const int*  ei  = (const int*)d_in[1];
  const void* WE  = d_in[2];
  const void* bE  = d_in[3];
  const void* gam = d_in[4];
  const void* bet = d_in[5];
  const void* W1  = d_in[6];
  const void* b1  = d_in[7];
  const void* W2  = d_in[8];
  const void* b2  = d_in[9];

  float* wsf = (float*)d_ws;
  int*   wsi = (int*)d_ws;
  int*   deg   = wsi + 0;          // NN (zeroed)
  int*   fill  = wsi + 100000;     // NN (zeroed)
  float* bnsum = wsf + 200000;     // 64 (zeroed)
  float* bnsq  = wsf + 200064;     // 64 (zeroed)
  int*   flags = wsi + 200128;     // 8
  float* bnab  = wsf + 200136;     // 128
  float* dinv  = wsf + 200264;     // NN
  int*   offs  = wsi + 300264;     // NN+1
  int*   cbase = wsi + 400272;     // NCH (pad to 400384)
  unsigned short* w1hi = (unsigned short*)(wsi + 433152);  // 64*320
  unsigned short* w1lo = (unsigned short*)(wsi + 443392);
  unsigned short* w2hi = (unsigned short*)(wsi + 453632);  // 40*64
  unsigned short* w2lo = (unsigned short*)(wsi + 454912);
  int2*  ep    = (int2*)(wsi + 456192);   // 1.6M edges
  float* diag2 = wsf + 3656192;    // NN
  unsigned short* zhi  = (unsigned short*)(wsi + 10156192); // NN*320 bf16
  unsigned short* zlo  = (unsigned short*)(wsi + 26156192); // NN*320 bf16
  // quarter-major gather tables (NN*64 bf16 = 3.2M words each)
  unsigned short* g_hb  = (unsigned short*)(wsi + 42156192);
  unsigned short* g_h1  = (unsigned short*)(wsi + 45356192);
  unsigned short* g_cur = (unsigned short*)(wsi + 48556192);
  unsigned short* g_rep = (unsigned short*)(wsi + 51756192);
  // packed embed-W planes (64 KB each) reuse deg/fill (dead after k_fill)
  unsigned short* wph  = (unsigned short*)(wsi + 0);       // 64*512 bf16 hi
  unsigned short* wpl  = (unsigned short*)(wsi + 100000);  // 64*512 bf16 lo

  hipMemsetAsync(d_ws, 0, (size_t)200128 * 4, stream);

  k_probe     <<<1, 256, 0, stream>>>((const unsigned short*)x, ei, flags);
  k_wsplit    <<<(64 * ZD + 255) / 256, 256, 0, stream>>>(W1, flags, 64 * ZD, w1hi, w1lo);
  k_wsplit    <<<(CLS * HID + 255) / 256, 256, 0, stream>>>(W2, flags, CLS * HID, w2hi, w2lo);

  k_deg       <<<EE / 256, 256, 0, stream>>>(ei, flags, deg);
  k_chunksum  <<<NCH, 1024, 0, stream>>>(deg, cbase);
  k_scanchunks<<<1, 64, 0, stream>>>(cbase, offs + NN);
  k_offs      <<<NCH, 1024, 0, stream>>>(deg, cbase, offs, dinv);
  k_fill      <<<EE / 256, 256, 0, stream>>>(ei, flags, offs, fill, dinv, ep);

  k_wpack     <<<16, 256, 0, stream>>>(WE, flags, wph, wpl);
  k_embed     <<<NBLKE, 256, 0, stream>>>(x, wph, wpl, bE, flags, g_hb, bnsum, bnsq);
  k_bnfin     <<<1, 64, 0, stream>>>(bnsum, bnsq, gam, bet, flags, bnab);

  k_sp1<<<NN, 256, 0, stream>>>(offs, ep, g_hb, bnab, diag2, zhi, zlo, g_h1);
  k_sp2<<<NN, 256, 0, stream>>>(offs, ep, g_h1, diag2, zhi, zlo, g_cur);
  k_spg<<<NN, 256, 0, stream>>>(offs, ep, g_cur, diag2, nullptr, zhi, zlo, 192, g_rep);
  k_spg<<<NN, 256, 0, stream>>>(offs, ep, g_rep, diag2, g_cur, zhi, zlo, 256, nullptr);

  k_final<<<(NN / 32 + 3) / 4, 256, 0, stream>>>(zhi, zlo, w1hi, w1lo, b1,
                                                 w2hi, w2lo, b2, flags, d_out);
}

// Round 7
// 834.176 us; speedup vs baseline: 1.2061x; 1.2061x over previous
//
#include <hip/hip_runtime.h>
#include <stdint.h>

// H2GCN forward on MI355X (gfx950). Round 13:
//  - r12 post-mortem: channel-quartered SPMM regressed (VALUBusy 84.6% ->
//    4x edge-work replication; quarter tables not L2-resident). REVERTED to
//    r11 paired-edge SPMM (802us baseline).
//  - NEW: k_fill (135us, WRITE 101MB of random 8B scatters = 64B-line
//    write-allocate) replaced by binned 2-phase CSR build:
//    k_bin: append {r,c} into exact per-4-row-bucket CSR ranges (25000
//    cursors, k_deg-like contention; ~512B append windows -> L2 combines).
//    k_csr: 1 wave/bucket, coalesced bin read, LDS fill counters, recompute
//    w=dinv[r]*dinv[c] (L2-resident), windowed ep writes. ~26MB vs 101MB.
//  - k_embed (LDS-staged), SPMM (r11), k_final unchanged.

typedef __bf16 bf16x8 __attribute__((ext_vector_type(8)));
typedef float  f32x4  __attribute__((ext_vector_type(4)));

#define NN   100000
#define EE   800000
#define IND  512
#define HID  64
#define ZD   320
#define CLS  40
#define NCH  98           // ceil(NN/1024)
#define NBLKE 1563        // ceil(NN/64) embed blocks (4 waves x 16 rows)

static __device__ __forceinline__ float bf2f(unsigned short s) {
  unsigned int u = ((unsigned int)s) << 16;
  return __builtin_bit_cast(float, u);
}
static __device__ __forceinline__ unsigned short f2bf(float f) {
  unsigned int u = __builtin_bit_cast(unsigned int, f);
  u += 0x7FFFu + ((u >> 16) & 1u);   // RNE
  return (unsigned short)(u >> 16);
}
static __device__ __forceinline__ float ldsc(const void* p, int i, int fm) {
  return fm ? ((const float*)p)[i] : bf2f(((const unsigned short*)p)[i]);
}
static __device__ __forceinline__ float i2f(int v) { return __builtin_bit_cast(float, v); }
static __device__ __forceinline__ void split8r(f32x4 u0, f32x4 u1, bf16x8& hi, bf16x8& lo) {
  #pragma unroll
  for (int j = 0; j < 4; ++j) {
    float v0 = u0[j], v1 = u1[j];
    __bf16 h0 = (__bf16)v0, h1 = (__bf16)v1;
    hi[j] = h0;     lo[j] = (__bf16)(v0 - (float)h0);
    hi[4 + j] = h1; lo[4 + j] = (__bf16)(v1 - (float)h1);
  }
}
static __device__ __forceinline__ void splitsc(float v, unsigned short* hp, unsigned short* lp) {
  __bf16 h = (__bf16)v;
  *hp = __builtin_bit_cast(unsigned short, h);
  __bf16 l = (__bf16)(v - (float)h);
  *lp = __builtin_bit_cast(unsigned short, l);
}
// split 2 channels, pack, 4B stores to hi/lo planes
static __device__ __forceinline__ void split2(float x, float y,
                                              unsigned short* hp, unsigned short* lp) {
  __bf16 hx = (__bf16)x, hy = (__bf16)y;
  __bf16 lx = (__bf16)(x - (float)hx), ly = (__bf16)(y - (float)hy);
  unsigned int hw = (unsigned int)__builtin_bit_cast(unsigned short, hx)
                  | ((unsigned int)__builtin_bit_cast(unsigned short, hy) << 16);
  unsigned int lw = (unsigned int)__builtin_bit_cast(unsigned short, lx)
                  | ((unsigned int)__builtin_bit_cast(unsigned short, ly) << 16);
  *(unsigned int*)hp = hw;
  *(unsigned int*)lp = lw;
}
// async global->LDS, 16B per lane (dest = uniform base + lane*16)
static __device__ __forceinline__ void gload16(const void* g, void* l) {
  __builtin_amdgcn_global_load_lds(
      (const __attribute__((address_space(1))) void*)g,
      (__attribute__((address_space(3))) void*)l, 16, 0, 0);
}

// ---------------- dtype probe ----------------
__global__ void k_probe(const unsigned short* __restrict__ xs,
                        const int* __restrict__ ei, int* __restrict__ flags) {
  __shared__ int cnt_big, cnt_nz;
  if (threadIdx.x == 0) { cnt_big = 0; cnt_nz = 0; }
  __syncthreads();
  unsigned short u = xs[threadIdx.x];
  int expf = (u >> 7) & 0xFF;
  if (expf >= 0x8D) atomicAdd(&cnt_big, 1);
  if (threadIdx.x < 128 && ei[2 * threadIdx.x + 1] != 0) atomicAdd(&cnt_nz, 1);
  __syncthreads();
  if (threadIdx.x == 0) {
    flags[0] = (cnt_big >= 2) ? 1 : 0;
    flags[1] = (cnt_nz < 64) ? 1 : 0;
  }
}

// ---------------- weight pre-split (W1, W2) ----------------
__global__ void k_wsplit(const void* __restrict__ Wv, const int* __restrict__ flags,
                         int n, unsigned short* __restrict__ hi,
                         unsigned short* __restrict__ lo) {
  int i = blockIdx.x * 256 + threadIdx.x;
  if (i >= n) return;
  float v = ldsc(Wv, i, flags[0]);
  splitsc(v, hi + i, lo + i);
}

// ---------------- embed-W split + pack into MFMA fragment order -------------
__global__ void k_wpack(const void* __restrict__ Wv, const int* __restrict__ flags,
                        unsigned short* __restrict__ ph, unsigned short* __restrict__ pl) {
  int tid = blockIdx.x * 256 + threadIdx.x;
  if (tid >= 64 * 64) return;
  int f = tid >> 6, lane = tid & 63;
  int kk = f >> 2, nt = f & 3;
  int l15 = lane & 15, quad = lane >> 4;
  int fmv = flags[0];
  int src = (nt * 16 + l15) * IND + kk * 32 + quad * 8;
  size_t dst = ((size_t)f * 64 + lane) * 8;
  #pragma unroll
  for (int j = 0; j < 8; ++j) {
    float v = ldsc(Wv, src + j, fmv);
    splitsc(v, ph + dst + j, pl + dst + j);
  }
}

// ---------------- graph build ----------------
__global__ void k_deg(const int* __restrict__ ei, const int* __restrict__ flags,
                      int* __restrict__ deg) {
  int e = blockIdx.x * 256 + threadIdx.x;
  if (e >= EE) return;
  int r, c;
  if (flags[1]) { r = ((const int2*)ei)[e].x; c = ((const int2*)ei)[EE + e].x; }
  else          { r = ei[e];                  c = ei[EE + e]; }
  if (r != c) { atomicAdd(&deg[r], 1); atomicAdd(&deg[c], 1); }
}

__global__ void k_chunksum(const int* __restrict__ deg, int* __restrict__ csum) {
  __shared__ int sd[1024];
  int i = blockIdx.x * 1024 + threadIdx.x;
  sd[threadIdx.x] = (i < NN) ? deg[i] : 0;
  __syncthreads();
  for (int s = 512; s > 0; s >>= 1) {
    if (threadIdx.x < s) sd[threadIdx.x] += sd[threadIdx.x + s];
    __syncthreads();
  }
  if (threadIdx.x == 0) csum[blockIdx.x] = sd[0];
}

__global__ void k_scanchunks(int* __restrict__ csum, int* __restrict__ total) {
  if (threadIdx.x == 0) {
    int acc = 0;
    for (int i = 0; i < NCH; ++i) { int v = csum[i]; csum[i] = acc; acc += v; }
    total[0] = acc;
  }
}

__global__ void k_offs(const int* __restrict__ deg, const int* __restrict__ cbase,
                       int* __restrict__ offs, float* __restrict__ dinv) {
  __shared__ int sd[1024];
  int i = blockIdx.x * 1024 + threadIdx.x;
  int v = (i < NN) ? deg[i] : 0;
  sd[threadIdx.x] = v;
  __syncthreads();
  for (int s = 1; s < 1024; s <<= 1) {
    int t = (threadIdx.x >= s) ? sd[threadIdx.x - s] : 0;
    __syncthreads();
    sd[threadIdx.x] += t;
    __syncthreads();
  }
  if (i < NN) {
    offs[i] = cbase[blockIdx.x] + sd[threadIdx.x] - v;
    dinv[i] = (v > 0) ? rsqrtf((float)v) : 0.f;
  }
}

// ---- binned 2-phase CSR build (replaces k_fill's 101MB random scatter) ----
// Bucket = 4 consecutive rows. k_bin appends {r,c} into the bucket's EXACT
// CSR range (capacity = sum of its rows' degrees -> no overflow possible).
__global__ void k_bin(const int* __restrict__ ei, const int* __restrict__ flags,
                      const int* __restrict__ offs, int* __restrict__ bcur,
                      int2* __restrict__ bins) {
  int e = blockIdx.x * 256 + threadIdx.x;
  if (e >= EE) return;
  int r, c;
  if (flags[1]) { r = ((const int2*)ei)[e].x; c = ((const int2*)ei)[EE + e].x; }
  else          { r = ei[e];                  c = ei[EE + e]; }
  if (r == c) return;
  int br = r >> 2, bc = c >> 2;
  int pr = offs[br << 2] + atomicAdd(&bcur[br], 1);
  bins[pr] = make_int2(r, c);
  int pc = offs[bc << 2] + atomicAdd(&bcur[bc], 1);
  bins[pc] = make_int2(c, r);
}

// 1 wave per bucket: coalesced bin read, LDS fill counters, w recomputed from
// L2-resident dinv, ep writes land in a ~512B window.
__global__ __launch_bounds__(64) void k_csr(const int* __restrict__ offs,
                                            const float* __restrict__ dinv,
                                            const int2* __restrict__ bins,
                                            int2* __restrict__ ep) {
  __shared__ int lfill[4];
  const int rowbase = blockIdx.x << 2;
  if (threadIdx.x < 4) lfill[threadIdx.x] = 0;
  __syncthreads();
  int beg = offs[rowbase], end = offs[rowbase + 4];
  for (int i = beg + (int)threadIdx.x; i < end; i += 64) {
    int2 rc = bins[i];
    int k = atomicAdd(&lfill[rc.x - rowbase], 1);
    float w = dinv[rc.x] * dinv[rc.y];
    ep[offs[rc.x] + k] = make_int2(rc.y, __builtin_bit_cast(int, w));
  }
}

// ---------------- embed GEMM: hb = bf16(relu(x @ W^T + b)), + BN stats -------
// v10 structure: block = 4 waves x 16 rows; x staged via global_load_lds,
// double-buffered; XOR swizzle both sides; W frags pinned before stage ops.
__global__ __launch_bounds__(256, 4) void k_embed(
    const void* __restrict__ xv,
    const unsigned short* __restrict__ wph, const unsigned short* __restrict__ wpl,
    const void* __restrict__ bEv, const int* __restrict__ flags,
    unsigned short* __restrict__ hb, float* __restrict__ bnsum, float* __restrict__ bnsq) {
  __shared__ char xb[2][16384] __attribute__((aligned(128)));
  __shared__ float ssum[4][64];
  __shared__ float ssq[4][64];
  const int fm = flags[0];
  const int wave = threadIdx.x >> 6, lane = threadIdx.x & 63;
  const int l15 = lane & 15, quad = lane >> 4;
  const int rb = blockIdx.x * 64;
  const int rbw = rb + wave * 16;
  f32x4 acc[4] = {};
  if (fm) {
    const char* sp[4];
    {
      const int borig = (l15 ^ (quad & 1)) * 16;
      #pragma unroll
      for (int j = 0; j < 4; ++j) {
        int grow = rb + (wave * 4 + j) * 4 + quad;
        if (grow > NN - 1) grow = NN - 1;
        sp[j] = (const char*)xv + (size_t)grow * 2048 + borig;
      }
    }
    const int p = l15 & 1;
    const int roA = (wave * 16 + l15) * 256 + quad * 32 + 16 * p;
    const int roB = (wave * 16 + l15) * 256 + quad * 32 + 16 - 16 * p;
    #pragma unroll
    for (int j = 0; j < 4; ++j)
      gload16(sp[j], &xb[0][(wave * 4 + j) * 1024]);
    __syncthreads();
    for (int c = 0; c < 8; ++c) {
      const int cur = c & 1;
      bf16x8 bh[2][4], bl[2][4];
      #pragma unroll
      for (int ks = 0; ks < 2; ++ks)
        #pragma unroll
        for (int nt = 0; nt < 4; ++nt) {
          size_t off = ((size_t)((c * 2 + ks) * 4 + nt) * 64 + lane) * 8;
          bh[ks][nt] = *(const bf16x8*)(wph + off);
          bl[ks][nt] = *(const bf16x8*)(wpl + off);
        }
      __builtin_amdgcn_sched_barrier(0);
      if (c < 7) {
        char* db = &xb[cur ^ 1][0];
        #pragma unroll
        for (int j = 0; j < 4; ++j)
          gload16(sp[j] + (c + 1) * 256, db + (wave * 4 + j) * 1024);
      }
      __builtin_amdgcn_sched_barrier(0);
      const char* cb = &xb[cur][0];
      #pragma unroll
      for (int ks = 0; ks < 2; ++ks) {
        f32x4 u0 = *(const f32x4*)(cb + roA + ks * 128);
        f32x4 u1 = *(const f32x4*)(cb + roB + ks * 128);
        bf16x8 ahi, alo;
        split8r(u0, u1, ahi, alo);
        #pragma unroll
        for (int nt = 0; nt < 4; ++nt) {
          acc[nt] = __builtin_amdgcn_mfma_f32_16x16x32_bf16(ahi, bh[ks][nt], acc[nt], 0, 0, 0);
          acc[nt] = __builtin_amdgcn_mfma_f32_16x16x32_bf16(alo, bh[ks][nt], acc[nt], 0, 0, 0);
          acc[nt] = __builtin_amdgcn_mfma_f32_16x16x32_bf16(ahi, bl[ks][nt], acc[nt], 0, 0, 0);
        }
      }
      __syncthreads();
    }
  } else {
    int row0 = rbw + l15; if (row0 > NN - 1) row0 = NN - 1;
    const unsigned short* xr0 = (const unsigned short*)xv + (size_t)row0 * IND + quad * 8;
    for (int kk = 0; kk < 16; ++kk) {
      bf16x8 bh[4];
      #pragma unroll
      for (int nt = 0; nt < 4; ++nt)
        bh[nt] = *(const bf16x8*)(wph + ((size_t)(kk * 4 + nt) * 64 + lane) * 8);
      bf16x8 a0 = *(const bf16x8*)(xr0 + kk * 32);
      #pragma unroll
      for (int nt = 0; nt < 4; ++nt)
        acc[nt] = __builtin_amdgcn_mfma_f32_16x16x32_bf16(a0, bh[nt], acc[nt], 0, 0, 0);
    }
  }
  #pragma unroll
  for (int nt = 0; nt < 4; ++nt) {
    int n = nt * 16 + l15;
    float bb = ldsc(bEv, n, fm);
    float ps = 0.f, pq = 0.f;
    #pragma unroll
    for (int r = 0; r < 4; ++r) {
      int row = rbw + quad * 4 + r;
      if (row < NN) {
        float v = fmaxf(acc[nt][r] + bb, 0.f);
        hb[(size_t)row * 64 + n] = f2bf(v);
        ps += v; pq += v * v;
      }
    }
    ps += __shfl_xor(ps, 16); pq += __shfl_xor(pq, 16);
    ps += __shfl_xor(ps, 32); pq += __shfl_xor(pq, 32);
    if (quad == 0) { ssum[wave][n] = ps; ssq[wave][n] = pq; }
  }
  __syncthreads();
  if (threadIdx.x < 64) {
    int c = threadIdx.x;
    float s = ssum[0][c] + ssum[1][c] + ssum[2][c] + ssum[3][c];
    float q = ssq[0][c] + ssq[1][c] + ssq[2][c] + ssq[3][c];
    atomicAdd(&bnsum[c], s);
    atomicAdd(&bnsq[c], q);
  }
}

__global__ void k_bnfin(const float* __restrict__ bnsum, const float* __restrict__ bnsq,
                        const void* __restrict__ gv, const void* __restrict__ bv,
                        const int* __restrict__ flags, float* __restrict__ ab) {
  int c = threadIdx.x;
  int fm = flags[0];
  if (c < 64) {
    float mu = bnsum[c] * (1.0f / (float)NN);
    float var = bnsq[c] * (1.0f / (float)NN) - mu * mu;
    float a = ldsc(gv, c, fm) / sqrtf(var + 1e-5f);
    float b = ldsc(bv, c, fm) - mu * a;
    ab[c] = a; ab[64 + c] = b;
  }
}

// ---------------- SPMM: paired-edge gather (r11) ----------------
#define PGATHER(SRC, STRIDE)                                                    \
  float2 a2[8] = {};                                                            \
  float sw = 0.f, sq = 0.f; (void)sq;                                           \
  {                                                                             \
    const int npairs = (e - s + 1) >> 1;                                        \
    int i = 0;                                                                  \
    for (; i + 8 <= npairs; i += 8) {                                           \
      int2 q[8]; float w[8];                                                    \
      _Pragma("unroll") for (int t = 0; t < 8; ++t) {                           \
        int jj = s + 2 * (i + t) + hh;                                          \
        bool ok = jj < e;                                                       \
        q[t] = ep[ok ? jj : s];                                                 \
        w[t] = ok ? i2f(q[t].y) : 0.f;                                          \
      }                                                                         \
      unsigned int v[8];                                                        \
      _Pragma("unroll") for (int t = 0; t < 8; ++t)                             \
        v[t] = *(const unsigned int*)(SRC + (size_t)q[t].x * STRIDE + 2 * c2);  \
      _Pragma("unroll") for (int t = 0; t < 8; ++t) {                           \
        a2[t].x = fmaf(w[t], bf2f((unsigned short)(v[t] & 0xffff)), a2[t].x);   \
        a2[t].y = fmaf(w[t], bf2f((unsigned short)(v[t] >> 16)), a2[t].y);      \
        sw += w[t]; sq = fmaf(w[t], w[t], sq);                                  \
      }                                                                         \
    }                                                                           \
    for (; i < npairs; ++i) {                                                   \
      int jj = s + 2 * i + hh;                                                  \
      bool ok = jj < e;                                                         \
      int2 q = ep[ok ? jj : s];                                                 \
      float w = ok ? i2f(q.y) : 0.f;                                            \
      unsigned int v = *(const unsigned int*)(SRC + (size_t)q.x * STRIDE + 2 * c2); \
      a2[0].x = fmaf(w, bf2f((unsigned short)(v & 0xffff)), a2[0].x);           \
      a2[0].y = fmaf(w, bf2f((unsigned short)(v >> 16)), a2[0].y);              \
      sw += w; sq = fmaf(w, w, sq);                                             \
    }                                                                           \
  }                                                                             \
  float accx = ((a2[0].x + a2[1].x) + (a2[2].x + a2[3].x))                      \
             + ((a2[4].x + a2[5].x) + (a2[6].x + a2[7].x));                     \
  float accy = ((a2[0].y + a2[1].y) + (a2[2].y + a2[3].y))                      \
             + ((a2[4].y + a2[5].y) + (a2[6].y + a2[7].y));                     \
  accx += __shfl_xor(accx, 32); accy += __shfl_xor(accy, 32);                   \
  sw   += __shfl_xor(sw, 32);   sq   += __shfl_xor(sq, 32);

// SPMM1: gather hb; block0 = BN(hb[r]); block1 = h1; diag2 = Sum(w^2)
__global__ __launch_bounds__(256) void k_sp1(
    const int* __restrict__ offs, const int2* __restrict__ ep,
    const unsigned short* __restrict__ hb, const float* __restrict__ bnab,
    float* __restrict__ diag2,
    unsigned short* __restrict__ zhi, unsigned short* __restrict__ zlo) {
  const int r = blockIdx.x * 4 + (threadIdx.x >> 6);
  const int lane = threadIdx.x & 63;
  const int hh = lane >> 5, c2 = lane & 31;
  if (r >= NN) return;
  int s = offs[r], e = offs[r + 1];
  PGATHER(hb, 64)
  float2 ga = *(const float2*)(bnab + 2 * c2);
  float2 gb = *(const float2*)(bnab + 64 + 2 * c2);
  size_t zr = (size_t)r * ZD;
  unsigned int hv = *(const unsigned int*)(hb + (size_t)r * 64 + 2 * c2);
  float z0x = fmaf(ga.x, bf2f((unsigned short)(hv & 0xffff)), gb.x);
  float z0y = fmaf(ga.y, bf2f((unsigned short)(hv >> 16)), gb.y);
  float h1x = ga.x * accx + gb.x * sw;
  float h1y = ga.y * accy + gb.y * sw;
  if (hh == 0) {
    split2(z0x, z0y, zhi + zr + 2 * c2, zlo + zr + 2 * c2);
    split2(h1x, h1y, zhi + zr + 64 + 2 * c2, zlo + zr + 64 + 2 * c2);
  }
  if (lane == 0) diag2[r] = sq;
}

// SPMM2: gather block1(hi); h2 = acc - diag2*z0; block2 = h2; curb = bf16(h1+h2)
__global__ __launch_bounds__(256) void k_sp2(
    const int* __restrict__ offs, const int2* __restrict__ ep,
    const float* __restrict__ diag2,
    unsigned short* __restrict__ zhi, unsigned short* __restrict__ zlo,
    unsigned short* __restrict__ curb) {
  const int r = blockIdx.x * 4 + (threadIdx.x >> 6);
  const int lane = threadIdx.x & 63;
  const int hh = lane >> 5, c2 = lane & 31;
  if (r >= NN) return;
  int s = offs[r], e = offs[r + 1];
  const unsigned short* src = zhi + 64;
  PGATHER(src, ZD)
  size_t zr = (size_t)r * ZD;
  unsigned int zh0 = *(const unsigned int*)(zhi + zr + 2 * c2);
  unsigned int zl0 = *(const unsigned int*)(zlo + zr + 2 * c2);
  unsigned int zh1 = *(const unsigned int*)(zhi + zr + 64 + 2 * c2);
  unsigned int zl1 = *(const unsigned int*)(zlo + zr + 64 + 2 * c2);
  float z0x = bf2f((unsigned short)(zh0 & 0xffff)) + bf2f((unsigned short)(zl0 & 0xffff));
  float z0y = bf2f((unsigned short)(zh0 >> 16)) + bf2f((unsigned short)(zl0 >> 16));
  float h1x = bf2f((unsigned short)(zh1 & 0xffff)) + bf2f((unsigned short)(zl1 & 0xffff));
  float h1y = bf2f((unsigned short)(zh1 >> 16)) + bf2f((unsigned short)(zl1 >> 16));
  float d2 = diag2[r];
  float h2x = accx - d2 * z0x;
  float h2y = accy - d2 * z0y;
  if (hh == 0) {
    split2(h2x, h2y, zhi + zr + 128 + 2 * c2, zlo + zr + 128 + 2 * c2);
    unsigned int cw = (unsigned int)f2bf(h1x + h2x) | ((unsigned int)f2bf(h1y + h2y) << 16);
    *(unsigned int*)(curb + (size_t)r * 64 + 2 * c2) = cw;
  }
}

// SPMM3/4: gather src (stride ss); y = acc [- diag2*bf(corrb)]; block zoff = y
__global__ __launch_bounds__(256) void k_spg(
    const int* __restrict__ offs, const int2* __restrict__ ep,
    const unsigned short* __restrict__ src, long ss,
    const float* __restrict__ diag2, const unsigned short* __restrict__ corrb,
    unsigned short* __restrict__ zhi, unsigned short* __restrict__ zlo, long zoff) {
  const int r = blockIdx.x * 4 + (threadIdx.x >> 6);
  const int lane = threadIdx.x & 63;
  const int hh = lane >> 5, c2 = lane & 31;
  if (r >= NN) return;
  int s = offs[r], e = offs[r + 1];
  PGATHER(src, ss)
  if (corrb) {
    float d2 = diag2[r];
    unsigned int cv = *(const unsigned int*)(corrb + (size_t)r * 64 + 2 * c2);
    accx -= d2 * bf2f((unsigned short)(cv & 0xffff));
    accy -= d2 * bf2f((unsigned short)(cv >> 16));
  }
  if (hh == 0) {
    size_t zi = (size_t)r * ZD + zoff + 2 * c2;
    split2(accx, accy, zhi + zi, zlo + zi);
  }
}

// ---------------- final: out = relu(z @ W1^T + b1) @ W2^T + b2 ----------------
__global__ __launch_bounds__(256) void k_final(
    const unsigned short* __restrict__ zhi, const unsigned short* __restrict__ zlo,
    const unsigned short* __restrict__ w1hi, const unsigned short* __restrict__ w1lo,
    const void* __restrict__ b1v,
    const unsigned short* __restrict__ w2hi, const unsigned short* __restrict__ w2lo,
    const void* __restrict__ b2v,
    const int* __restrict__ flags, void* __restrict__ outv) {
  __shared__ float tls[4][2][16][68];
  const int fm = flags[0];
  const int wave = threadIdx.x >> 6, lane = threadIdx.x & 63;
  const int l15 = lane & 15, quad = lane >> 4;
  const int gid = blockIdx.x * 4 + wave;      // 0..3124 valid (32 rows each)
  const bool valid = gid < NN / 32;
  if (valid) {
    const int rb = gid * 32;
    f32x4 acc[2][4] = {};
    size_t zb[2];
    #pragma unroll
    for (int t = 0; t < 2; ++t)
      zb[t] = (size_t)(rb + t * 16 + l15) * ZD + quad * 8;
    for (int ks = 0; ks < 10; ++ks) {
      bf16x8 ahi[2], alo[2];
      #pragma unroll
      for (int t = 0; t < 2; ++t) {
        ahi[t] = *(const bf16x8*)(zhi + zb[t] + ks * 32);
        alo[t] = *(const bf16x8*)(zlo + zb[t] + ks * 32);
      }
      #pragma unroll
      for (int nt = 0; nt < 4; ++nt) {
        size_t wb = (size_t)(nt * 16 + l15) * ZD + ks * 32 + quad * 8;
        bf16x8 bhi = *(const bf16x8*)(w1hi + wb);
        bf16x8 blo = *(const bf16x8*)(w1lo + wb);
        #pragma unroll
        for (int t = 0; t < 2; ++t) {
          acc[t][nt] = __builtin_amdgcn_mfma_f32_16x16x32_bf16(ahi[t], bhi, acc[t][nt], 0, 0, 0);
          acc[t][nt] = __builtin_amdgcn_mfma_f32_16x16x32_bf16(alo[t], bhi, acc[t][nt], 0, 0, 0);
          acc[t][nt] = __builtin_amdgcn_mfma_f32_16x16x32_bf16(ahi[t], blo, acc[t][nt], 0, 0, 0);
        }
      }
    }
    #pragma unroll
    for (int nt = 0; nt < 4; ++nt) {
      int n = nt * 16 + l15;
      float bb = ldsc(b1v, n, fm);
      #pragma unroll
      for (int t = 0; t < 2; ++t)
        #pragma unroll
        for (int r = 0; r < 4; ++r)
          tls[wave][t][quad * 4 + r][n] = fmaxf(acc[t][nt][r] + bb, 0.f);
    }
  }
  __syncthreads();
  if (valid) {
    const int rb = gid * 32;
    f32x4 acc2[2][3] = {};
    #pragma unroll
    for (int ks = 0; ks < 2; ++ks) {
      bf16x8 ahi[2], alo[2];
      #pragma unroll
      for (int t = 0; t < 2; ++t)
        #pragma unroll
        for (int j = 0; j < 8; ++j) {
          float v = tls[wave][t][l15][ks * 32 + quad * 8 + j];
          __bf16 h = (__bf16)v;
          ahi[t][j] = h; alo[t][j] = (__bf16)(v - (float)h);
        }
      #pragma unroll
      for (int nt = 0; nt < 3; ++nt) {
        int n = nt * 16 + l15;
        bf16x8 bhi = {}, blo = {};
        if (n < CLS) {
          size_t wb = (size_t)n * HID + ks * 32 + quad * 8;
          bhi = *(const bf16x8*)(w2hi + wb);
          blo = *(const bf16x8*)(w2lo + wb);
        }
        #pragma unroll
        for (int t = 0; t < 2; ++t) {
          acc2[t][nt] = __builtin_amdgcn_mfma_f32_16x16x32_bf16(ahi[t], bhi, acc2[t][nt], 0, 0, 0);
          acc2[t][nt] = __builtin_amdgcn_mfma_f32_16x16x32_bf16(alo[t], bhi, acc2[t][nt], 0, 0, 0);
          acc2[t][nt] = __builtin_amdgcn_mfma_f32_16x16x32_bf16(ahi[t], blo, acc2[t][nt], 0, 0, 0);
        }
      }
    }
    #pragma unroll
    for (int nt = 0; nt < 3; ++nt) {
      int n = nt * 16 + l15;
      if (n < CLS) {
        float bb = ldsc(b2v, n, fm);
        #pragma unroll
        for (int t = 0; t < 2; ++t)
          #pragma unroll
          for (int r = 0; r < 4; ++r) {
            float v = acc2[t][nt][r] + bb;
            size_t oi = (size_t)(rb + t * 16 + quad * 4 + r) * CLS + n;
            if (fm) ((float*)outv)[oi] = v;
            else    ((unsigned short*)outv)[oi] = f2bf(v);
          }
      }
    }
  }
}

extern "C" void kernel_launch(void* const* d_in, const int* in_sizes, int n_in,
                              void* d_out, int out_size, void* d_ws, size_t ws_size,
                              hipStream_t stream) {
  (void)in_sizes; (void)n_in; (void)out_size; (void)ws_size;
  const void* x   = d_in[0];
  const int*  ei  = (const int*)d_in[1];
  const void* WE  = d_in[2];
  const void* bE  = d_in[3];
  const void* gam = d_in[4];
  const void* bet = d_in[5];
  const void* W1  = d_in[6];
  const void* b1  = d_in[7];
  const void* W2  = d_in[8];
  const void* b2  = d_in[9];

  float* wsf = (float*)d_ws;
  int*   wsi = (int*)d_ws;
  int*   deg   = wsi + 0;          // NN (zeroed)
  int*   bcur  = wsi + 100000;     // 25000 bucket cursors (zeroed)
  float* bnsum = wsf + 200000;     // 64 (zeroed)
  float* bnsq  = wsf + 200064;     // 64 (zeroed)
  int*   flags = wsi + 200128;     // 8
  float* bnab  = wsf + 200136;     // 128
  float* dinv  = wsf + 200264;     // NN
  int*   offs  = wsi + 300264;     // NN+1
  int*   cbase = wsi + 400272;     // NCH (pad to 400384)
  unsigned short* w1hi = (unsigned short*)(wsi + 433152);  // 64*320
  unsigned short* w1lo = (unsigned short*)(wsi + 443392);
  unsigned short* w2hi = (unsigned short*)(wsi + 453632);  // 40*64
  unsigned short* w2lo = (unsigned short*)(wsi + 454912);
  int2*  ep    = (int2*)(wsi + 456192);   // 1.6M edges
  float* diag2 = wsf + 3656192;    // NN
  unsigned short* hb   = (unsigned short*)(wsi + 3756192);  // NN*64 bf16
  unsigned short* curb = (unsigned short*)(wsi + 6956192);  // NN*64 bf16
  unsigned short* zhi  = (unsigned short*)(wsi + 10156192); // NN*320 bf16
  unsigned short* zlo  = (unsigned short*)(wsi + 26156192); // NN*320 bf16
  int2*  bins  = (int2*)(wsi + 42156192);  // 1.6M edge bins
  // packed embed-W planes (64 KB each) reuse deg/bcur (dead after k_csr)
  unsigned short* wph  = (unsigned short*)(wsi + 0);       // 64*512 bf16 hi
  unsigned short* wpl  = (unsigned short*)(wsi + 100000);  // 64*512 bf16 lo

  hipMemsetAsync(d_ws, 0, (size_t)200128 * 4, stream);

  k_probe     <<<1, 256, 0, stream>>>((const unsigned short*)x, ei, flags);
  k_wsplit    <<<(64 * ZD + 255) / 256, 256, 0, stream>>>(W1, flags, 64 * ZD, w1hi, w1lo);
  k_wsplit    <<<(CLS * HID + 255) / 256, 256, 0, stream>>>(W2, flags, CLS * HID, w2hi, w2lo);

  k_deg       <<<EE / 256, 256, 0, stream>>>(ei, flags, deg);
  k_chunksum  <<<NCH, 1024, 0, stream>>>(deg, cbase);
  k_scanchunks<<<1, 64, 0, stream>>>(cbase, offs + NN);
  k_offs      <<<NCH, 1024, 0, stream>>>(deg, cbase, offs, dinv);
  k_bin       <<<EE / 256, 256, 0, stream>>>(ei, flags, offs, bcur, bins);
  k_csr       <<<NN / 4, 64, 0, stream>>>(offs, dinv, bins, ep);

  k_wpack     <<<16, 256, 0, stream>>>(WE, flags, wph, wpl);
  k_embed     <<<NBLKE, 256, 0, stream>>>(x, wph, wpl, bE, flags, hb, bnsum, bnsq);
  k_bnfin     <<<1, 64, 0, stream>>>(bnsum, bnsq, gam, bet, flags, bnab);

  k_sp1<<<NN / 4, 256, 0, stream>>>(offs, ep, hb, bnab, diag2, zhi, zlo);
  k_sp2<<<NN / 4, 256, 0, stream>>>(offs, ep, diag2, zhi, zlo, curb);
  k_spg<<<NN / 4, 256, 0, stream>>>(offs, ep, curb, 64, diag2, nullptr, zhi, zlo, 192);
  k_spg<<<NN / 4, 256, 0, stream>>>(offs, ep, zhi + 192, ZD, diag2, curb, zhi, zlo, 256);

  k_final<<<(NN / 32 + 3) / 4, 256, 0, stream>>>(zhi, zlo, w1hi, w1lo, b1,
                                                 w2hi, w2lo, b2, flags, d_out);
}

// Round 8
// 739.771 us; speedup vs baseline: 1.3600x; 1.1276x over previous
//
#include <hip/hip_runtime.h>
#include <stdint.h>

// H2GCN forward on MI355X (gfx950). Round 14:
//  - r13 post-mortem: k_bin (global-cursor appends) = 117.8us, WRITE 102.8MB
//    -- identical to k_fill. Scatters only get cheaper with IN-CU (LDS)
//    write-combining flushed as full 64B lines.
//  - NEW build chain: k_bin2 (LDS rings per 1024-row bucket, full-line
//    flushes, 12.8MB writes) -> k_scanb -> k_hist (bucket histogram+scan =>
//    offs,dinv -- k_deg/k_offs DELETED) -> k_place (ep within L2-resident
//    bucket windows). Replaces k_deg/k_chunksum/k_scanchunks/k_offs/k_fill.
//  - SPMM = r11 paired-edge gather (proven best). k_embed/k_final unchanged.

typedef __bf16 bf16x8 __attribute__((ext_vector_type(8)));
typedef float  f32x4  __attribute__((ext_vector_type(4)));

#define NN   100000
#define EE   800000
#define IND  512
#define HID  64
#define ZD   320
#define CLS  40
#define NBLKE 1563        // ceil(NN/64) embed blocks (4 waves x 16 rows)
#define NB   98           // buckets of 1024 rows
#define BCAP 20480        // edges per bucket (mean 16384 + 32 sigma)
#define BDEP 64           // LDS ring depth

static __device__ __forceinline__ float bf2f(unsigned short s) {
  unsigned int u = ((unsigned int)s) << 16;
  return __builtin_bit_cast(float, u);
}
static __device__ __forceinline__ unsigned short f2bf(float f) {
  unsigned int u = __builtin_bit_cast(unsigned int, f);
  u += 0x7FFFu + ((u >> 16) & 1u);   // RNE
  return (unsigned short)(u >> 16);
}
static __device__ __forceinline__ float ldsc(const void* p, int i, int fm) {
  return fm ? ((const float*)p)[i] : bf2f(((const unsigned short*)p)[i]);
}
static __device__ __forceinline__ float i2f(int v) { return __builtin_bit_cast(float, v); }
static __device__ __forceinline__ void split8r(f32x4 u0, f32x4 u1, bf16x8& hi, bf16x8& lo) {
  #pragma unroll
  for (int j = 0; j < 4; ++j) {
    float v0 = u0[j], v1 = u1[j];
    __bf16 h0 = (__bf16)v0, h1 = (__bf16)v1;
    hi[j] = h0;     lo[j] = (__bf16)(v0 - (float)h0);
    hi[4 + j] = h1; lo[4 + j] = (__bf16)(v1 - (float)h1);
  }
}
static __device__ __forceinline__ void splitsc(float v, unsigned short* hp, unsigned short* lp) {
  __bf16 h = (__bf16)v;
  *hp = __builtin_bit_cast(unsigned short, h);
  __bf16 l = (__bf16)(v - (float)h);
  *lp = __builtin_bit_cast(unsigned short, l);
}
// split 2 channels, pack, 4B stores to hi/lo planes
static __device__ __forceinline__ void split2(float x, float y,
                                              unsigned short* hp, unsigned short* lp) {
  __bf16 hx = (__bf16)x, hy = (__bf16)y;
  __bf16 lx = (__bf16)(x - (float)hx), ly = (__bf16)(y - (float)hy);
  unsigned int hw = (unsigned int)__builtin_bit_cast(unsigned short, hx)
                  | ((unsigned int)__builtin_bit_cast(unsigned short, hy) << 16);
  unsigned int lw = (unsigned int)__builtin_bit_cast(unsigned short, lx)
                  | ((unsigned int)__builtin_bit_cast(unsigned short, ly) << 16);
  *(unsigned int*)hp = hw;
  *(unsigned int*)lp = lw;
}
// async global->LDS, 16B per lane (dest = uniform base + lane*16)
static __device__ __forceinline__ void gload16(const void* g, void* l) {
  __builtin_amdgcn_global_load_lds(
      (const __attribute__((address_space(1))) void*)g,
      (__attribute__((address_space(3))) void*)l, 16, 0, 0);
}

// ---------------- dtype probe ----------------
__global__ void k_probe(const unsigned short* __restrict__ xs,
                        const int* __restrict__ ei, int* __restrict__ flags) {
  __shared__ int cnt_big, cnt_nz;
  if (threadIdx.x == 0) { cnt_big = 0; cnt_nz = 0; }
  __syncthreads();
  unsigned short u = xs[threadIdx.x];
  int expf = (u >> 7) & 0xFF;
  if (expf >= 0x8D) atomicAdd(&cnt_big, 1);
  if (threadIdx.x < 128 && ei[2 * threadIdx.x + 1] != 0) atomicAdd(&cnt_nz, 1);
  __syncthreads();
  if (threadIdx.x == 0) {
    flags[0] = (cnt_big >= 2) ? 1 : 0;
    flags[1] = (cnt_nz < 64) ? 1 : 0;
  }
}

// ---------------- weight pre-split (W1, W2) ----------------
__global__ void k_wsplit(const void* __restrict__ Wv, const int* __restrict__ flags,
                         int n, unsigned short* __restrict__ hi,
                         unsigned short* __restrict__ lo) {
  int i = blockIdx.x * 256 + threadIdx.x;
  if (i >= n) return;
  float v = ldsc(Wv, i, flags[0]);
  splitsc(v, hi + i, lo + i);
}

// ---------------- embed-W split + pack into MFMA fragment order -------------
__global__ void k_wpack(const void* __restrict__ Wv, const int* __restrict__ flags,
                        unsigned short* __restrict__ ph, unsigned short* __restrict__ pl) {
  int tid = blockIdx.x * 256 + threadIdx.x;
  if (tid >= 64 * 64) return;
  int f = tid >> 6, lane = tid & 63;
  int kk = f >> 2, nt = f & 3;
  int l15 = lane & 15, quad = lane >> 4;
  int fmv = flags[0];
  int src = (nt * 16 + l15) * IND + kk * 32 + quad * 8;
  size_t dst = ((size_t)f * 64 + lane) * 8;
  #pragma unroll
  for (int j = 0; j < 8; ++j) {
    float v = ldsc(Wv, src + j, fmv);
    splitsc(v, ph + dst + j, pl + dst + j);
  }
}

// ---------------- graph build: LDS-ring binning ----------------
// 256 blocks x 256 threads; block owns 3125 edges (256*3125 = EE exactly).
// Edges appended to per-bucket LDS rings; flusher threads emit full 64B
// lines (8 edges) per global atomic. gcur counters padded to 64B.
__global__ __launch_bounds__(256) void k_bin2(const int* __restrict__ ei,
                                              const int* __restrict__ flags,
                                              int* __restrict__ gcur,
                                              int2* __restrict__ bins) {
  __shared__ int2 ring[NB][BDEP];    // 50,176 B
  __shared__ int rtail[NB], rhead[NB];
  const int tid = threadIdx.x;
  for (int b = tid; b < NB; b += 256) { rtail[b] = 0; rhead[b] = 0; }
  __syncthreads();
  const int base = blockIdx.x * 3125;
  const int fm64 = flags[1];
  for (int it = 0; it < 13; ++it) {
    int e = base + it * 256 + tid;
    if (e < base + 3125) {
      int r, c;
      if (fm64) { r = ((const int2*)ei)[e].x; c = ((const int2*)ei)[EE + e].x; }
      else      { r = ei[e];                  c = ei[EE + e]; }
      if (r != c) {
        int br = r >> 10, bc = c >> 10;
        int k1 = atomicAdd(&rtail[br], 1);
        ring[br][k1 & (BDEP - 1)] = make_int2(r, c);
        int k2 = atomicAdd(&rtail[bc], 1);
        ring[bc][k2 & (BDEP - 1)] = make_int2(c, r);
      }
    }
    __syncthreads();
    if (tid < NB) {
      int h = rhead[tid], t = rtail[tid];
      while (t - h >= 8) {
        int slot = atomicAdd(&gcur[tid * 16], 8);
        int2* dst = bins + (size_t)tid * BCAP + slot;
        #pragma unroll
        for (int j = 0; j < 8; ++j) dst[j] = ring[tid][(h + j) & (BDEP - 1)];
        h += 8;
      }
      rhead[tid] = h;
    }
    __syncthreads();
  }
  if (tid < NB) {
    int h = rhead[tid], n = rtail[tid] - h;
    if (n > 0) {
      int slot = atomicAdd(&gcur[tid * 16], n);
      int2* dst = bins + (size_t)tid * BCAP + slot;
      for (int j = 0; j < n; ++j) dst[j] = ring[tid][(h + j) & (BDEP - 1)];
    }
  }
}

// scan bucket counts -> bucket bases; offs[NN] = total
__global__ void k_scanb(const int* __restrict__ gcur, int* __restrict__ bbase,
                        int* __restrict__ offs) {
  if (threadIdx.x == 0) {
    int acc = 0;
    for (int b = 0; b < NB; ++b) { bbase[b] = acc; acc += gcur[b * 16]; }
    offs[NN] = acc;
  }
}

// per-bucket row histogram + scan -> offs, dinv (replaces k_deg/k_offs)
__global__ __launch_bounds__(1024) void k_hist(const int* __restrict__ gcur,
                                               const int* __restrict__ bbase,
                                               const int2* __restrict__ bins,
                                               int* __restrict__ offs,
                                               float* __restrict__ dinv) {
  __shared__ int lh[1024];
  const int b = blockIdx.x, tid = threadIdx.x;
  lh[tid] = 0;
  __syncthreads();
  const int cnt = gcur[b * 16];
  const int2* src = bins + (size_t)b * BCAP;
  for (int i = tid; i < cnt; i += 1024)
    atomicAdd(&lh[src[i].x & 1023], 1);
  __syncthreads();
  int deg = lh[tid];
  for (int s = 1; s < 1024; s <<= 1) {
    int t = (tid >= s) ? lh[tid - s] : 0;
    __syncthreads();
    lh[tid] += t;
    __syncthreads();
  }
  int row = b * 1024 + tid;
  if (row < NN) {
    offs[row] = bbase[b] + lh[tid] - deg;
    dinv[row] = (deg > 0) ? rsqrtf((float)deg) : 0.f;
  }
}

// place edges into CSR (writes land in the bucket's ~130KB L2 window)
__global__ __launch_bounds__(1024) void k_place(const int* __restrict__ gcur,
                                                const int2* __restrict__ bins,
                                                const int* __restrict__ offs,
                                                const float* __restrict__ dinv,
                                                int2* __restrict__ ep) {
  __shared__ int lf[1024];
  const int b = blockIdx.x, tid = threadIdx.x;
  lf[tid] = 0;
  __syncthreads();
  const int cnt = gcur[b * 16];
  const int2* src = bins + (size_t)b * BCAP;
  for (int i = tid; i < cnt; i += 1024) {
    int2 rc = src[i];
    int k = atomicAdd(&lf[rc.x & 1023], 1);
    float w = dinv[rc.x] * dinv[rc.y];
    ep[offs[rc.x] + k] = make_int2(rc.y, __builtin_bit_cast(int, w));
  }
}

// ---------------- embed GEMM: hb = bf16(relu(x @ W^T + b)), + BN stats -------
__global__ __launch_bounds__(256, 4) void k_embed(
    const void* __restrict__ xv,
    const unsigned short* __restrict__ wph, const unsigned short* __restrict__ wpl,
    const void* __restrict__ bEv, const int* __restrict__ flags,
    unsigned short* __restrict__ hb, float* __restrict__ bnsum, float* __restrict__ bnsq) {
  __shared__ char xb[2][16384] __attribute__((aligned(128)));
  __shared__ float ssum[4][64];
  __shared__ float ssq[4][64];
  const int fm = flags[0];
  const int wave = threadIdx.x >> 6, lane = threadIdx.x & 63;
  const int l15 = lane & 15, quad = lane >> 4;
  const int rb = blockIdx.x * 64;
  const int rbw = rb + wave * 16;
  f32x4 acc[4] = {};
  if (fm) {
    const char* sp[4];
    {
      const int borig = (l15 ^ (quad & 1)) * 16;
      #pragma unroll
      for (int j = 0; j < 4; ++j) {
        int grow = rb + (wave * 4 + j) * 4 + quad;
        if (grow > NN - 1) grow = NN - 1;
        sp[j] = (const char*)xv + (size_t)grow * 2048 + borig;
      }
    }
    const int p = l15 & 1;
    const int roA = (wave * 16 + l15) * 256 + quad * 32 + 16 * p;
    const int roB = (wave * 16 + l15) * 256 + quad * 32 + 16 - 16 * p;
    #pragma unroll
    for (int j = 0; j < 4; ++j)
      gload16(sp[j], &xb[0][(wave * 4 + j) * 1024]);
    __syncthreads();
    for (int c = 0; c < 8; ++c) {
      const int cur = c & 1;
      bf16x8 bh[2][4], bl[2][4];
      #pragma unroll
      for (int ks = 0; ks < 2; ++ks)
        #pragma unroll
        for (int nt = 0; nt < 4; ++nt) {
          size_t off = ((size_t)((c * 2 + ks) * 4 + nt) * 64 + lane) * 8;
          bh[ks][nt] = *(const bf16x8*)(wph + off);
          bl[ks][nt] = *(const bf16x8*)(wpl + off);
        }
      __builtin_amdgcn_sched_barrier(0);
      if (c < 7) {
        char* db = &xb[cur ^ 1][0];
        #pragma unroll
        for (int j = 0; j < 4; ++j)
          gload16(sp[j] + (c + 1) * 256, db + (wave * 4 + j) * 1024);
      }
      __builtin_amdgcn_sched_barrier(0);
      const char* cb = &xb[cur][0];
      #pragma unroll
      for (int ks = 0; ks < 2; ++ks) {
        f32x4 u0 = *(const f32x4*)(cb + roA + ks * 128);
        f32x4 u1 = *(const f32x4*)(cb + roB + ks * 128);
        bf16x8 ahi, alo;
        split8r(u0, u1, ahi, alo);
        #pragma unroll
        for (int nt = 0; nt < 4; ++nt) {
          acc[nt] = __builtin_amdgcn_mfma_f32_16x16x32_bf16(ahi, bh[ks][nt], acc[nt], 0, 0, 0);
          acc[nt] = __builtin_amdgcn_mfma_f32_16x16x32_bf16(alo, bh[ks][nt], acc[nt], 0, 0, 0);
          acc[nt] = __builtin_amdgcn_mfma_f32_16x16x32_bf16(ahi, bl[ks][nt], acc[nt], 0, 0, 0);
        }
      }
      __syncthreads();
    }
  } else {
    int row0 = rbw + l15; if (row0 > NN - 1) row0 = NN - 1;
    const unsigned short* xr0 = (const unsigned short*)xv + (size_t)row0 * IND + quad * 8;
    for (int kk = 0; kk < 16; ++kk) {
      bf16x8 bh[4];
      #pragma unroll
      for (int nt = 0; nt < 4; ++nt)
        bh[nt] = *(const bf16x8*)(wph + ((size_t)(kk * 4 + nt) * 64 + lane) * 8);
      bf16x8 a0 = *(const bf16x8*)(xr0 + kk * 32);
      #pragma unroll
      for (int nt = 0; nt < 4; ++nt)
        acc[nt] = __builtin_amdgcn_mfma_f32_16x16x32_bf16(a0, bh[nt], acc[nt], 0, 0, 0);
    }
  }
  #pragma unroll
  for (int nt = 0; nt < 4; ++nt) {
    int n = nt * 16 + l15;
    float bb = ldsc(bEv, n, fm);
    float ps = 0.f, pq = 0.f;
    #pragma unroll
    for (int r = 0; r < 4; ++r) {
      int row = rbw + quad * 4 + r;
      if (row < NN) {
        float v = fmaxf(acc[nt][r] + bb, 0.f);
        hb[(size_t)row * 64 + n] = f2bf(v);
        ps += v; pq += v * v;
      }
    }
    ps += __shfl_xor(ps, 16); pq += __shfl_xor(pq, 16);
    ps += __shfl_xor(ps, 32); pq += __shfl_xor(pq, 32);
    if (quad == 0) { ssum[wave][n] = ps; ssq[wave][n] = pq; }
  }
  __syncthreads();
  if (threadIdx.x < 64) {
    int c = threadIdx.x;
    float s = ssum[0][c] + ssum[1][c] + ssum[2][c] + ssum[3][c];
    float q = ssq[0][c] + ssq[1][c] + ssq[2][c] + ssq[3][c];
    atomicAdd(&bnsum[c], s);
    atomicAdd(&bnsq[c], q);
  }
}

__global__ void k_bnfin(const float* __restrict__ bnsum, const float* __restrict__ bnsq,
                        const void* __restrict__ gv, const void* __restrict__ bv,
                        const int* __restrict__ flags, float* __restrict__ ab) {
  int c = threadIdx.x;
  int fm = flags[0];
  if (c < 64) {
    float mu = bnsum[c] * (1.0f / (float)NN);
    float var = bnsq[c] * (1.0f / (float)NN) - mu * mu;
    float a = ldsc(gv, c, fm) / sqrtf(var + 1e-5f);
    float b = ldsc(bv, c, fm) - mu * a;
    ab[c] = a; ab[64 + c] = b;
  }
}

// ---------------- SPMM: paired-edge gather (r11) ----------------
#define PGATHER(SRC, STRIDE)                                                    \
  float2 a2[8] = {};                                                            \
  float sw = 0.f, sq = 0.f; (void)sq;                                           \
  {                                                                             \
    const int npairs = (e - s + 1) >> 1;                                        \
    int i = 0;                                                                  \
    for (; i + 8 <= npairs; i += 8) {                                           \
      int2 q[8]; float w[8];                                                    \
      _Pragma("unroll") for (int t = 0; t < 8; ++t) {                           \
        int jj = s + 2 * (i + t) + hh;                                          \
        bool ok = jj < e;                                                       \
        q[t] = ep[ok ? jj : s];                                                 \
        w[t] = ok ? i2f(q[t].y) : 0.f;                                          \
      }                                                                         \
      unsigned int v[8];                                                        \
      _Pragma("unroll") for (int t = 0; t < 8; ++t)                             \
        v[t] = *(const unsigned int*)(SRC + (size_t)q[t].x * STRIDE + 2 * c2);  \
      _Pragma("unroll") for (int t = 0; t < 8; ++t) {                           \
        a2[t].x = fmaf(w[t], bf2f((unsigned short)(v[t] & 0xffff)), a2[t].x);   \
        a2[t].y = fmaf(w[t], bf2f((unsigned short)(v[t] >> 16)), a2[t].y);      \
        sw += w[t]; sq = fmaf(w[t], w[t], sq);                                  \
      }                                                                         \
    }                                                                           \
    for (; i < npairs; ++i) {                                                   \
      int jj = s + 2 * i + hh;                                                  \
      bool ok = jj < e;                                                         \
      int2 q = ep[ok ? jj : s];                                                 \
      float w = ok ? i2f(q.y) : 0.f;                                            \
      unsigned int v = *(const unsigned int*)(SRC + (size_t)q.x * STRIDE + 2 * c2); \
      a2[0].x = fmaf(w, bf2f((unsigned short)(v & 0xffff)), a2[0].x);           \
      a2[0].y = fmaf(w, bf2f((unsigned short)(v >> 16)), a2[0].y);              \
      sw += w; sq = fmaf(w, w, sq);                                             \
    }                                                                           \
  }                                                                             \
  float accx = ((a2[0].x + a2[1].x) + (a2[2].x + a2[3].x))                      \
             + ((a2[4].x + a2[5].x) + (a2[6].x + a2[7].x));                     \
  float accy = ((a2[0].y + a2[1].y) + (a2[2].y + a2[3].y))                      \
             + ((a2[4].y + a2[5].y) + (a2[6].y + a2[7].y));                     \
  accx += __shfl_xor(accx, 32); accy += __shfl_xor(accy, 32);                   \
  sw   += __shfl_xor(sw, 32);   sq   += __shfl_xor(sq, 32);

// SPMM1: gather hb; block0 = BN(hb[r]); block1 = h1; diag2 = Sum(w^2)
__global__ __launch_bounds__(256) void k_sp1(
    const int* __restrict__ offs, const int2* __restrict__ ep,
    const unsigned short* __restrict__ hb, const float* __restrict__ bnab,
    float* __restrict__ diag2,
    unsigned short* __restrict__ zhi, unsigned short* __restrict__ zlo) {
  const int r = blockIdx.x * 4 + (threadIdx.x >> 6);
  const int lane = threadIdx.x & 63;
  const int hh = lane >> 5, c2 = lane & 31;
  if (r >= NN) return;
  int s = offs[r], e = offs[r + 1];
  PGATHER(hb, 64)
  float2 ga = *(const float2*)(bnab + 2 * c2);
  float2 gb = *(const float2*)(bnab + 64 + 2 * c2);
  size_t zr = (size_t)r * ZD;
  unsigned int hv = *(const unsigned int*)(hb + (size_t)r * 64 + 2 * c2);
  float z0x = fmaf(ga.x, bf2f((unsigned short)(hv & 0xffff)), gb.x);
  float z0y = fmaf(ga.y, bf2f((unsigned short)(hv >> 16)), gb.y);
  float h1x = ga.x * accx + gb.x * sw;
  float h1y = ga.y * accy + gb.y * sw;
  if (hh == 0) {
    split2(z0x, z0y, zhi + zr + 2 * c2, zlo + zr + 2 * c2);
    split2(h1x, h1y, zhi + zr + 64 + 2 * c2, zlo + zr + 64 + 2 * c2);
  }
  if (lane == 0) diag2[r] = sq;
}

// SPMM2: gather block1(hi); h2 = acc - diag2*z0; block2 = h2; curb = bf16(h1+h2)
__global__ __launch_bounds__(256) void k_sp2(
    const int* __restrict__ offs, const int2* __restrict__ ep,
    const float* __restrict__ diag2,
    unsigned short* __restrict__ zhi, unsigned short* __restrict__ zlo,
    unsigned short* __restrict__ curb) {
  const int r = blockIdx.x * 4 + (threadIdx.x >> 6);
  const int lane = threadIdx.x & 63;
  const int hh = lane >> 5, c2 = lane & 31;
  if (r >= NN) return;
  int s = offs[r], e = offs[r + 1];
  const unsigned short* src = zhi + 64;
  PGATHER(src, ZD)
  size_t zr = (size_t)r * ZD;
  unsigned int zh0 = *(const unsigned int*)(zhi + zr + 2 * c2);
  unsigned int zl0 = *(const unsigned int*)(zlo + zr + 2 * c2);
  unsigned int zh1 = *(const unsigned int*)(zhi + zr + 64 + 2 * c2);
  unsigned int zl1 = *(const unsigned int*)(zlo + zr + 64 + 2 * c2);
  float z0x = bf2f((unsigned short)(zh0 & 0xffff)) + bf2f((unsigned short)(zl0 & 0xffff));
  float z0y = bf2f((unsigned short)(zh0 >> 16)) + bf2f((unsigned short)(zl0 >> 16));
  float h1x = bf2f((unsigned short)(zh1 & 0xffff)) + bf2f((unsigned short)(zl1 & 0xffff));
  float h1y = bf2f((unsigned short)(zh1 >> 16)) + bf2f((unsigned short)(zl1 >> 16));
  float d2 = diag2[r];
  float h2x = accx - d2 * z0x;
  float h2y = accy - d2 * z0y;
  if (hh == 0) {
    split2(h2x, h2y, zhi + zr + 128 + 2 * c2, zlo + zr + 128 + 2 * c2);
    unsigned int cw = (unsigned int)f2bf(h1x + h2x) | ((unsigned int)f2bf(h1y + h2y) << 16);
    *(unsigned int*)(curb + (size_t)r * 64 + 2 * c2) = cw;
  }
}

// SPMM3/4: gather src (stride ss); y = acc [- diag2*bf(corrb)]; block zoff = y
__global__ __launch_bounds__(256) void k_spg(
    const int* __restrict__ offs, const int2* __restrict__ ep,
    const unsigned short* __restrict__ src, long ss,
    const float* __restrict__ diag2, const unsigned short* __restrict__ corrb,
    unsigned short* __restrict__ zhi, unsigned short* __restrict__ zlo, long zoff) {
  const int r = blockIdx.x * 4 + (threadIdx.x >> 6);
  const int lane = threadIdx.x & 63;
  const int hh = lane >> 5, c2 = lane & 31;
  if (r >= NN) return;
  int s = offs[r], e = offs[r + 1];
  PGATHER(src, ss)
  if (corrb) {
    float d2 = diag2[r];
    unsigned int cv = *(const unsigned int*)(corrb + (size_t)r * 64 + 2 * c2);
    accx -= d2 * bf2f((unsigned short)(cv & 0xffff));
    accy -= d2 * bf2f((unsigned short)(cv >> 16));
  }
  if (hh == 0) {
    size_t zi = (size_t)r * ZD + zoff + 2 * c2;
    split2(accx, accy, zhi + zi, zlo + zi);
  }
}

// ---------------- final: out = relu(z @ W1^T + b1) @ W2^T + b2 ----------------
__global__ __launch_bounds__(256) void k_final(
    const unsigned short* __restrict__ zhi, const unsigned short* __restrict__ zlo,
    const unsigned short* __restrict__ w1hi, const unsigned short* __restrict__ w1lo,
    const void* __restrict__ b1v,
    const unsigned short* __restrict__ w2hi, const unsigned short* __restrict__ w2lo,
    const void* __restrict__ b2v,
    const int* __restrict__ flags, void* __restrict__ outv) {
  __shared__ float tls[4][2][16][68];
  const int fm = flags[0];
  const int wave = threadIdx.x >> 6, lane = threadIdx.x & 63;
  const int l15 = lane & 15, quad = lane >> 4;
  const int gid = blockIdx.x * 4 + wave;      // 0..3124 valid (32 rows each)
  const bool valid = gid < NN / 32;
  if (valid) {
    const int rb = gid * 32;
    f32x4 acc[2][4] = {};
    size_t zb[2];
    #pragma unroll
    for (int t = 0; t < 2; ++t)
      zb[t] = (size_t)(rb + t * 16 + l15) * ZD + quad * 8;
    for (int ks = 0; ks < 10; ++ks) {
      bf16x8 ahi[2], alo[2];
      #pragma unroll
      for (int t = 0; t < 2; ++t) {
        ahi[t] = *(const bf16x8*)(zhi + zb[t] + ks * 32);
        alo[t] = *(const bf16x8*)(zlo + zb[t] + ks * 32);
      }
      #pragma unroll
      for (int nt = 0; nt < 4; ++nt) {
        size_t wb = (size_t)(nt * 16 + l15) * ZD + ks * 32 + quad * 8;
        bf16x8 bhi = *(const bf16x8*)(w1hi + wb);
        bf16x8 blo = *(const bf16x8*)(w1lo + wb);
        #pragma unroll
        for (int t = 0; t < 2; ++t) {
          acc[t][nt] = __builtin_amdgcn_mfma_f32_16x16x32_bf16(ahi[t], bhi, acc[t][nt], 0, 0, 0);
          acc[t][nt] = __builtin_amdgcn_mfma_f32_16x16x32_bf16(alo[t], bhi, acc[t][nt], 0, 0, 0);
          acc[t][nt] = __builtin_amdgcn_mfma_f32_16x16x32_bf16(ahi[t], blo, acc[t][nt], 0, 0, 0);
        }
      }
    }
    #pragma unroll
    for (int nt = 0; nt < 4; ++nt) {
      int n = nt * 16 + l15;
      float bb = ldsc(b1v, n, fm);
      #pragma unroll
      for (int t = 0; t < 2; ++t)
        #pragma unroll
        for (int r = 0; r < 4; ++r)
          tls[wave][t][quad * 4 + r][n] = fmaxf(acc[t][nt][r] + bb, 0.f);
    }
  }
  __syncthreads();
  if (valid) {
    const int rb = gid * 32;
    f32x4 acc2[2][3] = {};
    #pragma unroll
    for (int ks = 0; ks < 2; ++ks) {
      bf16x8 ahi[2], alo[2];
      #pragma unroll
      for (int t = 0; t < 2; ++t)
        #pragma unroll
        for (int j = 0; j < 8; ++j) {
          float v = tls[wave][t][l15][ks * 32 + quad * 8 + j];
          __bf16 h = (__bf16)v;
          ahi[t][j] = h; alo[t][j] = (__bf16)(v - (float)h);
        }
      #pragma unroll
      for (int nt = 0; nt < 3; ++nt) {
        int n = nt * 16 + l15;
        bf16x8 bhi = {}, blo = {};
        if (n < CLS) {
          size_t wb = (size_t)n * HID + ks * 32 + quad * 8;
          bhi = *(const bf16x8*)(w2hi + wb);
          blo = *(const bf16x8*)(w2lo + wb);
        }
        #pragma unroll
        for (int t = 0; t < 2; ++t) {
          acc2[t][nt] = __builtin_amdgcn_mfma_f32_16x16x32_bf16(ahi[t], bhi, acc2[t][nt], 0, 0, 0);
          acc2[t][nt] = __builtin_amdgcn_mfma_f32_16x16x32_bf16(alo[t], bhi, acc2[t][nt], 0, 0, 0);
          acc2[t][nt] = __builtin_amdgcn_mfma_f32_16x16x32_bf16(ahi[t], blo, acc2[t][nt], 0, 0, 0);
        }
      }
    }
    #pragma unroll
    for (int nt = 0; nt < 3; ++nt) {
      int n = nt * 16 + l15;
      if (n < CLS) {
        float bb = ldsc(b2v, n, fm);
        #pragma unroll
        for (int t = 0; t < 2; ++t)
          #pragma unroll
          for (int r = 0; r < 4; ++r) {
            float v = acc2[t][nt][r] + bb;
            size_t oi = (size_t)(rb + t * 16 + quad * 4 + r) * CLS + n;
            if (fm) ((float*)outv)[oi] = v;
            else    ((unsigned short*)outv)[oi] = f2bf(v);
          }
      }
    }
  }
}

extern "C" void kernel_launch(void* const* d_in, const int* in_sizes, int n_in,
                              void* d_out, int out_size, void* d_ws, size_t ws_size,
                              hipStream_t stream) {
  (void)in_sizes; (void)n_in; (void)out_size; (void)ws_size;
  const void* x   = d_in[0];
  const int*  ei  = (const int*)d_in[1];
  const void* WE  = d_in[2];
  const void* bE  = d_in[3];
  const void* gam = d_in[4];
  const void* bet = d_in[5];
  const void* W1  = d_in[6];
  const void* b1  = d_in[7];
  const void* W2  = d_in[8];
  const void* b2  = d_in[9];

  float* wsf = (float*)d_ws;
  int*   wsi = (int*)d_ws;
  int*   gcur  = wsi + 0;          // 98*16 ints, 64B-padded counters (zeroed)
  unsigned short* wph = (unsigned short*)(wsi + 4096);    // 64*512 bf16 (after build)
  unsigned short* wpl = (unsigned short*)(wsi + 100000);  // 64*512 bf16 (after build)
  float* bnsum = wsf + 200000;     // 64 (zeroed)
  float* bnsq  = wsf + 200064;     // 64 (zeroed)
  int*   flags = wsi + 200128;     // 8
  float* bnab  = wsf + 200136;     // 128
  float* dinv  = wsf + 200264;     // NN (written by k_hist)
  int*   offs  = wsi + 300264;     // NN+1 (k_hist + k_scanb)
  int*   bbase = wsi + 400272;     // NB+1
  unsigned short* w1hi = (unsigned short*)(wsi + 433152);  // 64*320
  unsigned short* w1lo = (unsigned short*)(wsi + 443392);
  unsigned short* w2hi = (unsigned short*)(wsi + 453632);  // 40*64
  unsigned short* w2lo = (unsigned short*)(wsi + 454912);
  int2*  ep    = (int2*)(wsi + 456192);   // 1.6M edges
  float* diag2 = wsf + 3656192;    // NN
  unsigned short* hb   = (unsigned short*)(wsi + 3756192);  // NN*64 bf16
  unsigned short* curb = (unsigned short*)(wsi + 6956192);  // NN*64 bf16
  unsigned short* zhi  = (unsigned short*)(wsi + 10156192); // NN*320 bf16
  unsigned short* zlo  = (unsigned short*)(wsi + 26156192); // NN*320 bf16
  int2*  bins  = (int2*)(wsi + 42156192);  // NB*BCAP edges (16MB)

  hipMemsetAsync(d_ws, 0, (size_t)200128 * 4, stream);

  k_probe     <<<1, 256, 0, stream>>>((const unsigned short*)x, ei, flags);
  k_wsplit    <<<(64 * ZD + 255) / 256, 256, 0, stream>>>(W1, flags, 64 * ZD, w1hi, w1lo);
  k_wsplit    <<<(CLS * HID + 255) / 256, 256, 0, stream>>>(W2, flags, CLS * HID, w2hi, w2lo);

  k_bin2      <<<256, 256, 0, stream>>>(ei, flags, gcur, bins);
  k_scanb     <<<1, 64, 0, stream>>>(gcur, bbase, offs);
  k_hist      <<<NB, 1024, 0, stream>>>(gcur, bbase, bins, offs, dinv);
  k_place     <<<NB, 1024, 0, stream>>>(gcur, bins, offs, dinv, ep);

  k_wpack     <<<16, 256, 0, stream>>>(WE, flags, wph, wpl);
  k_embed     <<<NBLKE, 256, 0, stream>>>(x, wph, wpl, bE, flags, hb, bnsum, bnsq);
  k_bnfin     <<<1, 64, 0, stream>>>(bnsum, bnsq, gam, bet, flags, bnab);

  k_sp1<<<NN / 4, 256, 0, stream>>>(offs, ep, hb, bnab, diag2, zhi, zlo);
  k_sp2<<<NN / 4, 256, 0, stream>>>(offs, ep, diag2, zhi, zlo, curb);
  k_spg<<<NN / 4, 256, 0, stream>>>(offs, ep, curb, 64, diag2, nullptr, zhi, zlo, 192);
  k_spg<<<NN / 4, 256, 0, stream>>>(offs, ep, zhi + 192, ZD, diag2, curb, zhi, zlo, 256);

  k_final<<<(NN / 32 + 3) / 4, 256, 0, stream>>>(zhi, zlo, w1hi, w1lo, b1,
                                                 w2hi, w2lo, b2, flags, d_out);
}